// Round 2
// baseline (648.886 us; speedup 1.0000x reference)
//
#include <hip/hip_runtime.h>

// ---------------------------------------------------------------------------
// Fused QKV-proj + MHA (B=4,N=1024,D=1024,H=16,DH=64) with deterministic
// inverted dropout. All matmul paths use f16 MFMA; softmax-critical paths
// (proj for q/k, QK^T) use hi/lo f16 split 3-term products (~fp32 accuracy).
// R2: attention rebuilt barrier-free — K/V operands read directly from
// global (L2-resident, guide common-mistake #7), mask prefetched per tile,
// P through dedicated wave-private LDS. No __syncthreads in attn at all.
// ---------------------------------------------------------------------------

typedef _Float16 f16;
typedef _Float16 f16x4 __attribute__((ext_vector_type(4)));
typedef _Float16 f16x8 __attribute__((ext_vector_type(8)));
typedef float    f32x4 __attribute__((ext_vector_type(4)));

#define MFMA16(a, b, c) __builtin_amdgcn_mfma_f32_16x16x32_f16((a), (b), (c), 0, 0, 0)

__device__ __forceinline__ void gll16(const f16* g, f16* l) {
  __builtin_amdgcn_global_load_lds(
      (const __attribute__((address_space(1))) unsigned int*)g,
      (__attribute__((address_space(3))) unsigned int*)l, 16, 0, 0);
}

// --------------------------- convert fp32 -> hi/lo f16 ----------------------
__global__ __launch_bounds__(256) void cvt_split(const float4* __restrict__ s,
                                                 f16x4* __restrict__ hi,
                                                 f16x4* __restrict__ lo, int n4) {
  int i = blockIdx.x * 256 + threadIdx.x;
  if (i >= n4) return;
  float4 v = s[i];
  f16x4 h, l;
  h[0] = (f16)v.x; l[0] = (f16)(v.x - (float)h[0]);
  h[1] = (f16)v.y; l[1] = (f16)(v.y - (float)h[1]);
  h[2] = (f16)v.z; l[2] = (f16)(v.z - (float)h[2]);
  h[3] = (f16)v.w; l[3] = (f16)(v.w - (float)h[3]);
  hi[i] = h; lo[i] = l;
}

// --------------------------- QKV projection GEMM ----------------------------
// C[4096][3072] = query @ W^T + b; q/k columns via 3-term hi/lo, v via 1-term.
// 128x128 tile, BK=32, 4 waves, 16x16x32 MFMA (m97 structure).
__global__ __launch_bounds__(256) void proj_gemm(
    const f16* __restrict__ qh, const f16* __restrict__ ql,
    const f16* __restrict__ wh, const f16* __restrict__ wl,
    const float* __restrict__ bias,
    f16* __restrict__ Qh, f16* __restrict__ Ql,
    f16* __restrict__ Kh, f16* __restrict__ Kl,
    f16* __restrict__ Vh) {
  __shared__ f16 As[128 * 32];
  __shared__ f16 Bs[128 * 32];
  const int tid = threadIdx.x;
  const int m0 = blockIdx.y * 128, n0 = blockIdx.x * 128;
  const int wid = tid >> 6, lane = tid & 63;
  const int wm = (wid >> 1) * 64, wn = (wid & 1) * 64;
  const int r16 = lane & 15, g = lane >> 4;

  f32x4 zero4 = {0.f, 0.f, 0.f, 0.f};
  f32x4 acc[4][4];
#pragma unroll
  for (int i = 0; i < 4; ++i)
#pragma unroll
    for (int j = 0; j < 4; ++j) acc[i][j] = zero4;

  const f16* At[3] = {qh, ql, qh};
  const f16* Bt[3] = {wh, wh, wl};
  const int nsteps = (n0 < 2048) ? 96 : 32;  // v-cols need only the hi*hi term

  for (int s = 0; s < nsteps; ++s) {
    const int term = s >> 5, kk = (s & 31) << 5;
    const f16* Ab = At[term] + (size_t)m0 * 1024 + kk;
    const f16* Bb = Bt[term] + (size_t)n0 * 1024 + kk;
#pragma unroll
    for (int it = 0; it < 2; ++it) {
      int c = tid + it * 256;
      int row = c >> 2, cc = c & 3;
      gll16(Ab + row * 1024 + cc * 8, &As[c * 8]);
      gll16(Bb + row * 1024 + cc * 8, &Bs[c * 8]);
    }
    __syncthreads();
    f16x8 a[4], b[4];
#pragma unroll
    for (int i = 0; i < 4; ++i) {
      a[i] = *(const f16x8*)&As[(wm + i * 16 + r16) * 32 + g * 8];
      b[i] = *(const f16x8*)&Bs[(wn + i * 16 + r16) * 32 + g * 8];
    }
#pragma unroll
    for (int i = 0; i < 4; ++i)
#pragma unroll
      for (int j = 0; j < 4; ++j) acc[i][j] = MFMA16(a[i], b[j], acc[i][j]);
    __syncthreads();
  }

#pragma unroll
  for (int j = 0; j < 4; ++j) {
    const int col = n0 + wn + j * 16 + r16;
    const float bv = bias[col];
#pragma unroll
    for (int i = 0; i < 4; ++i) {
#pragma unroll
      for (int rr = 0; rr < 4; ++rr) {
        const int m = m0 + wm + i * 16 + g * 4 + rr;
        const float c = acc[i][j][rr] + bv;
        const int bi = m >> 10, n = m & 1023;
        if (col < 1024) {
          const int z = bi * 16 + (col >> 6), dh = col & 63;
          const size_t idx = ((size_t)z * 1024 + n) * 64 + dh;
          f16 h = (f16)c;
          Qh[idx] = h; Ql[idx] = (f16)(c - (float)h);
        } else if (col < 2048) {
          const int c2 = col - 1024;
          const int z = bi * 16 + (c2 >> 6), dh = c2 & 63;
          const size_t idx = ((size_t)z * 1024 + n) * 64 + dh;
          f16 h = (f16)c;
          Kh[idx] = h; Kl[idx] = (f16)(c - (float)h);
        } else {
          const int c2 = col - 2048;
          const int z = bi * 16 + (c2 >> 6), dh = c2 & 63;
          Vh[((size_t)z * 1024 + n) * 64 + dh] = (f16)c;
        }
      }
    }
  }
}

// --------------------------- V transpose ------------------------------------
__global__ __launch_bounds__(256) void transp_v(const f16* __restrict__ Vh,
                                                f16* __restrict__ Vt) {
  __shared__ f16 t[64][80];
  const int z = blockIdx.y, nt = blockIdx.x;
  const int tid = threadIdx.x;
#pragma unroll
  for (int it = 0; it < 2; ++it) {
    int c = tid + it * 256;
    int row = c >> 3, cc = c & 7;
    *(f16x8*)&t[row][cc * 8] =
        *(const f16x8*)&Vh[(((size_t)z << 10) + nt * 64 + row) * 64 + cc * 8];
  }
  __syncthreads();
#pragma unroll
  for (int it = 0; it < 2; ++it) {
    int c = tid + it * 256;
    int dh = c >> 3, ncc = c & 7;
    f16x8 o;
#pragma unroll
    for (int j = 0; j < 8; ++j) o[j] = t[ncc * 8 + j][dh];
    *(f16x8*)&Vt[((size_t)z * 64 + dh) * 1024 + nt * 64 + ncc * 8] = o;
  }
}

// --------------------------- fused attention (barrier-free) -----------------
// Per block: head z, 64 query rows (16 per wave). All MFMA operands except P
// come straight from global (L2-resident); P goes through a dedicated
// wave-private swizzled LDS tile. Zero __syncthreads.
__global__ __launch_bounds__(256) void attn(
    const f16* __restrict__ Qh_, const f16* __restrict__ Ql_,
    const f16* __restrict__ Kh_, const f16* __restrict__ Kl_,
    const f16* __restrict__ Vt_, const float* __restrict__ mask,
    float* __restrict__ out) {
  __shared__ f16 Ps[4][1024];  // per-wave 16x64 P tile (8 KB total)

  const int z = blockIdx.y, qt = blockIdx.x;
  const int q0 = qt * 64;
  const int tid = threadIdx.x, w = tid >> 6, lane = tid & 63;
  const int r16 = lane & 15, g = lane >> 4;

  // ---- Q fragments straight to registers (row = q0 + w*16 + r16) ----
  const f16* qrh = Qh_ + ((size_t)z * 1024 + q0 + w * 16 + r16) * 64;
  const f16* qrl = Ql_ + ((size_t)z * 1024 + q0 + w * 16 + r16) * 64;
  f16x8 qa[2], qla[2];
#pragma unroll
  for (int ks = 0; ks < 2; ++ks) {
    qa[ks] = *(const f16x8*)&qrh[ks * 32 + g * 8];
    qla[ks] = *(const f16x8*)&qrl[ks * 32 + g * 8];
  }

  const f16* Kzh = Kh_ + ((size_t)z << 10) * 64;
  const f16* Kzl = Kl_ + ((size_t)z << 10) * 64;
  const f16* Vz = Vt_ + (size_t)z * 64 * 1024;
  const float* mz = mask + ((size_t)z << 20);
  const int qrow_m = q0 + w * 16 + g * 4;  // + rr

  float mrow[4] = {-1e30f, -1e30f, -1e30f, -1e30f};
  float lrow[4] = {0.f, 0.f, 0.f, 0.f};
  f32x4 zero4 = {0.f, 0.f, 0.f, 0.f};
  f32x4 acc[4];
#pragma unroll
  for (int df = 0; df < 4; ++df) acc[df] = zero4;

  f16* Pw = &Ps[w][0];

  for (int kt = 0; kt < 16; ++kt) {
    const int k0 = kt * 64;

    // ---- mask tile loads issued FIRST (hide HBM latency under QK+softmax)
    float mv[4][4];
#pragma unroll
    for (int cf = 0; cf < 4; ++cf)
#pragma unroll
      for (int rr = 0; rr < 4; ++rr)
        mv[cf][rr] = mz[(size_t)(qrow_m + rr) * 1024 + k0 + cf * 16 + r16];

    // ---- S = Q K^T, 3-term hi/lo; K B-frags direct from global ----
    f32x4 s[4];
#pragma unroll
    for (int cf = 0; cf < 4; ++cf) {
      const f16* kb = Kzh + (size_t)(k0 + cf * 16 + r16) * 64;
      const f16* klb = Kzl + (size_t)(k0 + cf * 16 + r16) * 64;
      f16x8 kh0 = *(const f16x8*)&kb[g * 8];
      f16x8 kh1 = *(const f16x8*)&kb[32 + g * 8];
      f16x8 kl0 = *(const f16x8*)&klb[g * 8];
      f16x8 kl1 = *(const f16x8*)&klb[32 + g * 8];
      f32x4 t = zero4;
      t = MFMA16(qa[0], kh0, t);
      t = MFMA16(qla[0], kh0, t);
      t = MFMA16(qa[0], kl0, t);
      t = MFMA16(qa[1], kh1, t);
      t = MFMA16(qla[1], kh1, t);
      t = MFMA16(qa[1], kl1, t);
      s[cf] = t;
    }

    // ---- online softmax (scores *8 per reference quirk) ----
    float s8[4][4];
#pragma unroll
    for (int cf = 0; cf < 4; ++cf)
#pragma unroll
      for (int rr = 0; rr < 4; ++rr) s8[cf][rr] = s[cf][rr] * 8.0f;

    float rm[4];
#pragma unroll
    for (int rr = 0; rr < 4; ++rr)
      rm[rr] = fmaxf(fmaxf(s8[0][rr], s8[1][rr]), fmaxf(s8[2][rr], s8[3][rr]));
#pragma unroll
    for (int mk = 1; mk < 16; mk <<= 1)
#pragma unroll
      for (int rr = 0; rr < 4; ++rr)
        rm[rr] = fmaxf(rm[rr], __shfl_xor(rm[rr], mk, 64));

    float mnew[4], scal[4];
#pragma unroll
    for (int rr = 0; rr < 4; ++rr) {
      mnew[rr] = fmaxf(mrow[rr], rm[rr]);
      scal[rr] = __expf(mrow[rr] - mnew[rr]);
      mrow[rr] = mnew[rr];
    }

    float p_[4][4], rs[4] = {0.f, 0.f, 0.f, 0.f};
#pragma unroll
    for (int cf = 0; cf < 4; ++cf)
#pragma unroll
      for (int rr = 0; rr < 4; ++rr) {
        p_[cf][rr] = __expf(s8[cf][rr] - mnew[rr]);
        rs[rr] += p_[cf][rr];
      }
#pragma unroll
    for (int mk = 1; mk < 16; mk <<= 1)
#pragma unroll
      for (int rr = 0; rr < 4; ++rr) rs[rr] += __shfl_xor(rs[rr], mk, 64);
#pragma unroll
    for (int rr = 0; rr < 4; ++rr) lrow[rr] = lrow[rr] * scal[rr] + rs[rr];
#pragma unroll
    for (int df = 0; df < 4; ++df)
#pragma unroll
      for (int rr = 0; rr < 4; ++rr) acc[df][rr] *= scal[rr];

    // ---- dropout mask (post-softmax; denominator stays unmasked) ----
    // ---- write P (f16) into wave-private swizzled LDS; read A-frags ----
#pragma unroll
    for (int cf = 0; cf < 4; ++cf)
#pragma unroll
      for (int rr = 0; rr < 4; ++rr) {
        const int prow = g * 4 + rr, key = cf * 16 + r16;
        Pw[prow * 64 + (((key >> 3) ^ (prow & 7)) << 3) + (key & 7)] =
            (f16)(p_[cf][rr] * mv[cf][rr]);
      }
    f16x8 pf[2];
#pragma unroll
    for (int ks2 = 0; ks2 < 2; ++ks2) {
      const int row = r16, c = ks2 * 4 + g;
      pf[ks2] = *(const f16x8*)&Pw[row * 64 + ((c ^ (row & 7)) << 3)];
    }

    // ---- PV: V^T B-frags direct from global ----
#pragma unroll
    for (int df = 0; df < 4; ++df) {
      const f16* vb = Vz + (size_t)(df * 16 + r16) * 1024 + k0;
#pragma unroll
      for (int ks2 = 0; ks2 < 2; ++ks2)
        acc[df] =
            MFMA16(pf[ks2], *(const f16x8*)&vb[ks2 * 32 + g * 8], acc[df]);
    }
  }

  // ---- epilogue: out[b][n][h*64+dh] = acc / l ----
  const int bi = z >> 4, hh = z & 15;
#pragma unroll
  for (int df = 0; df < 4; ++df)
#pragma unroll
    for (int rr = 0; rr < 4; ++rr) {
      const int n = q0 + w * 16 + g * 4 + rr;
      out[((size_t)bi * 1024 + n) * 1024 + hh * 64 + df * 16 + r16] =
          acc[df][rr] / lrow[rr];
    }
}

// --------------------------- launcher ---------------------------------------
extern "C" void kernel_launch(void* const* d_in, const int* in_sizes, int n_in,
                              void* d_out, int out_size, void* d_ws,
                              size_t ws_size, hipStream_t stream) {
  const float* query = (const float*)d_in[0];
  const float* W = (const float*)d_in[3];
  const float* bias = (const float*)d_in[4];
  const float* mask = (const float*)d_in[5];
  float* out = (float*)d_out;

  f16* p = (f16*)d_ws;
  f16* qh = p;              p += (size_t)4096 * 1024;
  f16* ql = p;              p += (size_t)4096 * 1024;
  f16* wh = p;              p += (size_t)3072 * 1024;
  f16* wl = p;              p += (size_t)3072 * 1024;
  f16* Qh = p;              p += (size_t)64 * 1024 * 64;
  f16* Ql = p;              p += (size_t)64 * 1024 * 64;
  f16* Kh = p;              p += (size_t)64 * 1024 * 64;
  f16* Kl = p;              p += (size_t)64 * 1024 * 64;
  f16* Vh = p;              p += (size_t)64 * 1024 * 64;
  f16* Vt = p;

  cvt_split<<<(1048576 + 255) / 256, 256, 0, stream>>>(
      (const float4*)query, (f16x4*)qh, (f16x4*)ql, 1048576);
  cvt_split<<<(786432 + 255) / 256, 256, 0, stream>>>(
      (const float4*)W, (f16x4*)wh, (f16x4*)wl, 786432);
  proj_gemm<<<dim3(24, 32), 256, 0, stream>>>(qh, ql, wh, wl, bias, Qh, Ql, Kh,
                                              Kl, Vh);
  transp_v<<<dim3(16, 64), 256, 0, stream>>>(Vh, Vt);
  attn<<<dim3(16, 64), 256, 0, stream>>>(Qh, Ql, Kh, Kl, Vt, mask, out);
}

// Round 3
// 561.808 us; speedup vs baseline: 1.1550x; 1.1550x over previous
//
#include <hip/hip_runtime.h>

// ---------------------------------------------------------------------------
// Fused QKV-proj + MHA (B=4,N=1024,D=1024,H=16,DH=64), deterministic dropout.
// R3: attn = 8-wave 2-phase double-buffered LDS pipeline (T3-minimal),
//     proj = single-pass fused hi/lo (48 MFMA per barrier pair), XCD swizzle.
// ---------------------------------------------------------------------------

typedef _Float16 f16;
typedef _Float16 f16x4 __attribute__((ext_vector_type(4)));
typedef _Float16 f16x8 __attribute__((ext_vector_type(8)));
typedef float    f32x4 __attribute__((ext_vector_type(4)));

#define MFMA16(a, b, c) __builtin_amdgcn_mfma_f32_16x16x32_f16((a), (b), (c), 0, 0, 0)

__device__ __forceinline__ void gll16(const f16* g, f16* l) {
  __builtin_amdgcn_global_load_lds(
      (const __attribute__((address_space(1))) unsigned int*)g,
      (__attribute__((address_space(3))) unsigned int*)l, 16, 0, 0);
}

// swizzled fragment read from a [64 rows][64 f16] tile (128B rows, XOR-8 swz)
__device__ __forceinline__ f16x8 ldsfrag(const f16* tile, int row, int chunk) {
  return *(const f16x8*)&tile[row * 64 + ((chunk ^ (row & 7)) << 3)];
}

// --------------------------- convert fp32 -> hi/lo f16 ----------------------
__global__ __launch_bounds__(256) void cvt_split(const float4* __restrict__ s,
                                                 f16x4* __restrict__ hi,
                                                 f16x4* __restrict__ lo, int n4) {
  int i = blockIdx.x * 256 + threadIdx.x;
  if (i >= n4) return;
  float4 v = s[i];
  f16x4 h, l;
  h[0] = (f16)v.x; l[0] = (f16)(v.x - (float)h[0]);
  h[1] = (f16)v.y; l[1] = (f16)(v.y - (float)h[1]);
  h[2] = (f16)v.z; l[2] = (f16)(v.z - (float)h[2]);
  h[3] = (f16)v.w; l[3] = (f16)(v.w - (float)h[3]);
  hi[i] = h; lo[i] = l;
}

// --------------------------- QKV projection GEMM ----------------------------
// C[4096][3072] = query @ W^T + b. Single K-pass; per step stage Ah/Al/Bh/Bl
// and run 3-term hi/lo (q/k cols) or 1-term (v cols). 128x128, BK=32, 4 waves.
__global__ __launch_bounds__(256) void proj_gemm(
    const f16* __restrict__ qh, const f16* __restrict__ ql,
    const f16* __restrict__ wh, const f16* __restrict__ wl,
    const float* __restrict__ bias,
    f16* __restrict__ Qh, f16* __restrict__ Ql,
    f16* __restrict__ Kh, f16* __restrict__ Kl,
    f16* __restrict__ Vh) {
  __shared__ f16 Ah[128 * 32], Al[128 * 32], Bh[128 * 32], Bl[128 * 32];
  const int tid = threadIdx.x;
  // XCD-chunked swizzle (nwg=768, 768%8==0 -> bijective)
  const int bid = blockIdx.x;
  const int wg = (bid & 7) * 96 + (bid >> 3);
  const int m0 = (wg / 24) * 128, n0 = (wg % 24) * 128;
  const bool isv = (n0 >= 2048);
  const int wid = tid >> 6, lane = tid & 63;
  const int wm = (wid >> 1) * 64, wn = (wid & 1) * 64;
  const int r16 = lane & 15, g = lane >> 4;

  f32x4 zero4 = {0.f, 0.f, 0.f, 0.f};
  f32x4 acc[4][4];
#pragma unroll
  for (int i = 0; i < 4; ++i)
#pragma unroll
    for (int j = 0; j < 4; ++j) acc[i][j] = zero4;

  for (int s = 0; s < 32; ++s) {
    const int kk = s << 5;
    const f16* Abh = qh + (size_t)m0 * 1024 + kk;
    const f16* Abl = ql + (size_t)m0 * 1024 + kk;
    const f16* Bbh = wh + (size_t)n0 * 1024 + kk;
    const f16* Bbl = wl + (size_t)n0 * 1024 + kk;
#pragma unroll
    for (int it = 0; it < 2; ++it) {
      const int c = tid + it * 256;
      const int go = (c >> 2) * 1024 + (c & 3) * 8;
      gll16(Abh + go, &Ah[c * 8]);
      gll16(Bbh + go, &Bh[c * 8]);
      if (!isv) {
        gll16(Abl + go, &Al[c * 8]);
        gll16(Bbl + go, &Bl[c * 8]);
      }
    }
    __syncthreads();
    f16x8 a[4], al_[4];
#pragma unroll
    for (int i = 0; i < 4; ++i) {
      a[i] = *(const f16x8*)&Ah[(wm + i * 16 + r16) * 32 + g * 8];
      if (!isv) al_[i] = *(const f16x8*)&Al[(wm + i * 16 + r16) * 32 + g * 8];
    }
#pragma unroll
    for (int j = 0; j < 4; ++j) {
      const f16x8 b = *(const f16x8*)&Bh[(wn + j * 16 + r16) * 32 + g * 8];
      if (!isv) {
        const f16x8 bl = *(const f16x8*)&Bl[(wn + j * 16 + r16) * 32 + g * 8];
#pragma unroll
        for (int i = 0; i < 4; ++i) {
          acc[i][j] = MFMA16(a[i], b, acc[i][j]);
          acc[i][j] = MFMA16(al_[i], b, acc[i][j]);
          acc[i][j] = MFMA16(a[i], bl, acc[i][j]);
        }
      } else {
#pragma unroll
        for (int i = 0; i < 4; ++i) acc[i][j] = MFMA16(a[i], b, acc[i][j]);
      }
    }
    __syncthreads();
  }

  // epilogue: C layout col=lane&15, row=(lane>>4)*4+reg
#pragma unroll
  for (int j = 0; j < 4; ++j) {
    const int col = n0 + wn + j * 16 + r16;
    const float bv = bias[col];
#pragma unroll
    for (int i = 0; i < 4; ++i) {
#pragma unroll
      for (int rr = 0; rr < 4; ++rr) {
        const int m = m0 + wm + i * 16 + g * 4 + rr;
        const float c = acc[i][j][rr] + bv;
        const int bi = m >> 10, n = m & 1023;
        if (col < 1024) {
          const int z = bi * 16 + (col >> 6), dh = col & 63;
          const size_t idx = ((size_t)z * 1024 + n) * 64 + dh;
          f16 h = (f16)c;
          Qh[idx] = h; Ql[idx] = (f16)(c - (float)h);
        } else if (col < 2048) {
          const int c2 = col - 1024;
          const int z = bi * 16 + (c2 >> 6), dh = c2 & 63;
          const size_t idx = ((size_t)z * 1024 + n) * 64 + dh;
          f16 h = (f16)c;
          Kh[idx] = h; Kl[idx] = (f16)(c - (float)h);
        } else {
          const int c2 = col - 2048;
          const int z = bi * 16 + (c2 >> 6), dh = c2 & 63;
          Vh[((size_t)z * 1024 + n) * 64 + dh] = (f16)c;
        }
      }
    }
  }
}

// --------------------------- V transpose ------------------------------------
__global__ __launch_bounds__(256) void transp_v(const f16* __restrict__ Vh,
                                                f16* __restrict__ Vt) {
  __shared__ f16 t[64][80];
  const int z = blockIdx.y, nt = blockIdx.x;
  const int tid = threadIdx.x;
#pragma unroll
  for (int it = 0; it < 2; ++it) {
    int c = tid + it * 256;
    int row = c >> 3, cc = c & 7;
    *(f16x8*)&t[row][cc * 8] =
        *(const f16x8*)&Vh[(((size_t)z << 10) + nt * 64 + row) * 64 + cc * 8];
  }
  __syncthreads();
#pragma unroll
  for (int it = 0; it < 2; ++it) {
    int c = tid + it * 256;
    int dh = c >> 3, ncc = c & 7;
    f16x8 o;
#pragma unroll
    for (int j = 0; j < 8; ++j) o[j] = t[ncc * 8 + j][dh];
    *(f16x8*)&Vt[((size_t)z * 64 + dh) * 1024 + nt * 64 + ncc * 8] = o;
  }
}

// --------------------------- fused attention --------------------------------
// 8 waves (512 thr) per block; block = head z x 128 q-rows; 16 k-tiles of 64.
// 2-phase pipeline: STAGE(next) issued before compute(cur), one barrier/tile.
__global__ __launch_bounds__(512) void attn(
    const f16* __restrict__ Qh_, const f16* __restrict__ Ql_,
    const f16* __restrict__ Kh_, const f16* __restrict__ Kl_,
    const f16* __restrict__ Vt_, const float* __restrict__ mask,
    float* __restrict__ out) {
  __shared__ f16 Khs[2][4096], Kls[2][4096], Vts[2][4096];  // 48 KB dbuf
  __shared__ f16 Ps[8][1024];                               // 16 KB P tiles

  // XCD-chunked swizzle (nwg=512): each XCD gets 8 whole heads
  const int bid = blockIdx.x;
  const int wg = (bid & 7) * 64 + (bid >> 3);
  const int qt = wg & 7, z = wg >> 3;
  const int q0 = qt * 128;
  const int tid = threadIdx.x, w = tid >> 6, lane = tid & 63;
  const int r16 = lane & 15, g = lane >> 4;

  // ---- Q fragments straight to registers (rows q0 + w*16 + r16) ----
  const size_t zrow = (size_t)z << 10;
  const f16* qrh = Qh_ + (zrow + q0 + w * 16 + r16) * 64;
  const f16* qrl = Ql_ + (zrow + q0 + w * 16 + r16) * 64;
  f16x8 qa[2], qla[2];
#pragma unroll
  for (int ks = 0; ks < 2; ++ks) {
    qa[ks] = *(const f16x8*)&qrh[ks * 32 + g * 8];
    qla[ks] = *(const f16x8*)&qrl[ks * 32 + g * 8];
  }

  // staging geometry: one 16B chunk per thread per tile, XOR-8 pre-swizzled src
  const f16* KzhB = Kh_ + zrow * 64;
  const f16* KzlB = Kl_ + zrow * 64;
  const f16* VzB = Vt_ + (size_t)z * 64 * 1024;
  const int sc = tid, srow = sc >> 3, ssc = ((sc & 7) ^ (srow & 7)) << 3;

#define STAGE(buf, k0_)                                                   \
  do {                                                                    \
    gll16(KzhB + (size_t)((k0_) + srow) * 64 + ssc, &Khs[buf][sc * 8]);   \
    gll16(KzlB + (size_t)((k0_) + srow) * 64 + ssc, &Kls[buf][sc * 8]);   \
    gll16(VzB + (size_t)srow * 1024 + (k0_) + ssc, &Vts[buf][sc * 8]);    \
  } while (0)

  STAGE(0, 0);

  float mrow[4] = {-1e30f, -1e30f, -1e30f, -1e30f};
  float lrow[4] = {0.f, 0.f, 0.f, 0.f};
  f32x4 zero4 = {0.f, 0.f, 0.f, 0.f};
  f32x4 acc[4];
#pragma unroll
  for (int df = 0; df < 4; ++df) acc[df] = zero4;

  const float* mz = mask + ((size_t)z << 20);
  const int qrow_m = q0 + w * 16 + g * 4;
  f16* Pw = &Ps[w][0];
  __syncthreads();

  for (int kt = 0; kt < 16; ++kt) {
    const int cur = kt & 1;
    const int k0 = kt << 6;
    if (kt < 15) STAGE(cur ^ 1, k0 + 64);  // async prefetch of next tile

    // mask tile loads issued early (hide HBM latency under QK+softmax)
    float mv[4][4];
#pragma unroll
    for (int cf = 0; cf < 4; ++cf)
#pragma unroll
      for (int rr = 0; rr < 4; ++rr)
        mv[cf][rr] = mz[(size_t)(qrow_m + rr) * 1024 + k0 + cf * 16 + r16];

    // ---- S = Q K^T, 3-term hi/lo ----
    __builtin_amdgcn_s_setprio(1);
    f32x4 s[4];
#pragma unroll
    for (int cf = 0; cf < 4; ++cf) {
      const int krow = cf * 16 + r16;
      const f16x8 kh0 = ldsfrag(&Khs[cur][0], krow, g);
      const f16x8 kh1 = ldsfrag(&Khs[cur][0], krow, 4 + g);
      const f16x8 kl0 = ldsfrag(&Kls[cur][0], krow, g);
      const f16x8 kl1 = ldsfrag(&Kls[cur][0], krow, 4 + g);
      f32x4 t = zero4;
      t = MFMA16(qa[0], kh0, t);
      t = MFMA16(qla[0], kh0, t);
      t = MFMA16(qa[0], kl0, t);
      t = MFMA16(qa[1], kh1, t);
      t = MFMA16(qla[1], kh1, t);
      t = MFMA16(qa[1], kl1, t);
      s[cf] = t;
    }
    __builtin_amdgcn_s_setprio(0);

    // ---- online softmax (scores *8 per reference quirk) ----
    float s8[4][4];
#pragma unroll
    for (int cf = 0; cf < 4; ++cf)
#pragma unroll
      for (int rr = 0; rr < 4; ++rr) s8[cf][rr] = s[cf][rr] * 8.0f;

    float rm[4];
#pragma unroll
    for (int rr = 0; rr < 4; ++rr)
      rm[rr] = fmaxf(fmaxf(s8[0][rr], s8[1][rr]), fmaxf(s8[2][rr], s8[3][rr]));
#pragma unroll
    for (int mk = 1; mk < 16; mk <<= 1)
#pragma unroll
      for (int rr = 0; rr < 4; ++rr)
        rm[rr] = fmaxf(rm[rr], __shfl_xor(rm[rr], mk, 64));

    float mnew[4], scal[4];
#pragma unroll
    for (int rr = 0; rr < 4; ++rr) {
      mnew[rr] = fmaxf(mrow[rr], rm[rr]);
      scal[rr] = __expf(mrow[rr] - mnew[rr]);
      mrow[rr] = mnew[rr];
    }

    float p_[4][4], rs[4] = {0.f, 0.f, 0.f, 0.f};
#pragma unroll
    for (int cf = 0; cf < 4; ++cf)
#pragma unroll
      for (int rr = 0; rr < 4; ++rr) {
        p_[cf][rr] = __expf(s8[cf][rr] - mnew[rr]);
        rs[rr] += p_[cf][rr];
      }
#pragma unroll
    for (int mk = 1; mk < 16; mk <<= 1)
#pragma unroll
      for (int rr = 0; rr < 4; ++rr) rs[rr] += __shfl_xor(rs[rr], mk, 64);
#pragma unroll
    for (int rr = 0; rr < 4; ++rr) lrow[rr] = lrow[rr] * scal[rr] + rs[rr];
#pragma unroll
    for (int df = 0; df < 4; ++df)
#pragma unroll
      for (int rr = 0; rr < 4; ++rr) acc[df][rr] *= scal[rr];

    // ---- dropout + P (f16) through wave-private swizzled LDS ----
#pragma unroll
    for (int cf = 0; cf < 4; ++cf)
#pragma unroll
      for (int rr = 0; rr < 4; ++rr) {
        const int prow = g * 4 + rr, key = cf * 16 + r16;
        Pw[prow * 64 + (((key >> 3) ^ (prow & 7)) << 3) + (key & 7)] =
            (f16)(p_[cf][rr] * mv[cf][rr]);
      }
    f16x8 pf[2];
#pragma unroll
    for (int ks2 = 0; ks2 < 2; ++ks2)
      pf[ks2] = ldsfrag(Pw, r16, ks2 * 4 + g);

    // ---- PV from staged V^T tile ----
    __builtin_amdgcn_s_setprio(1);
#pragma unroll
    for (int df = 0; df < 4; ++df)
#pragma unroll
      for (int ks2 = 0; ks2 < 2; ++ks2)
        acc[df] = MFMA16(pf[ks2],
                         ldsfrag(&Vts[cur][0], df * 16 + r16, ks2 * 4 + g),
                         acc[df]);
    __builtin_amdgcn_s_setprio(0);
    __syncthreads();  // next tile staged + all reads of cur done
  }

  // ---- epilogue ----
  const int bi = z >> 4, hh = z & 15;
#pragma unroll
  for (int df = 0; df < 4; ++df)
#pragma unroll
    for (int rr = 0; rr < 4; ++rr) {
      const int n = q0 + w * 16 + g * 4 + rr;
      out[((size_t)bi * 1024 + n) * 1024 + hh * 64 + df * 16 + r16] =
          acc[df][rr] / lrow[rr];
    }
#undef STAGE
}

// --------------------------- launcher ---------------------------------------
extern "C" void kernel_launch(void* const* d_in, const int* in_sizes, int n_in,
                              void* d_out, int out_size, void* d_ws,
                              size_t ws_size, hipStream_t stream) {
  const float* query = (const float*)d_in[0];
  const float* W = (const float*)d_in[3];
  const float* bias = (const float*)d_in[4];
  const float* mask = (const float*)d_in[5];
  float* out = (float*)d_out;

  f16* p = (f16*)d_ws;
  f16* qh = p;              p += (size_t)4096 * 1024;
  f16* ql = p;              p += (size_t)4096 * 1024;
  f16* wh = p;              p += (size_t)3072 * 1024;
  f16* wl = p;              p += (size_t)3072 * 1024;
  f16* Qh = p;              p += (size_t)64 * 1024 * 64;
  f16* Ql = p;              p += (size_t)64 * 1024 * 64;
  f16* Kh = p;              p += (size_t)64 * 1024 * 64;
  f16* Kl = p;              p += (size_t)64 * 1024 * 64;
  f16* Vh = p;              p += (size_t)64 * 1024 * 64;
  f16* Vt = p;

  cvt_split<<<(1048576 + 255) / 256, 256, 0, stream>>>(
      (const float4*)query, (f16x4*)qh, (f16x4*)ql, 1048576);
  cvt_split<<<(786432 + 255) / 256, 256, 0, stream>>>(
      (const float4*)W, (f16x4*)wh, (f16x4*)wl, 786432);
  proj_gemm<<<768, 256, 0, stream>>>(qh, ql, wh, wl, bias, Qh, Ql, Kh, Kl, Vh);
  transp_v<<<dim3(16, 64), 256, 0, stream>>>(Vh, Vt);
  attn<<<512, 512, 0, stream>>>(Qh, Ql, Kh, Kl, Vt, mask, out);
}